// Round 7
// baseline (397.762 us; speedup 1.0000x reference)
//
#include <hip/hip_runtime.h>
#include <math.h>

#define T_FRAMES 16384
#define FDIM 2048
#define LQ 30
#define FPB 32    // frames per block
#define NTHR 1024 // 16 waves
#define FPW 2     // frames per wave

// ---------------------------------------------------------------------------
// Kernel 0: precompute per-head 7x7 bilinear forms (proven R1/R3/R5)
//   A_h[c][c2] = sum_d W_q[h*64+d][c] * W_k[h*64+d][c2]
//   M_h[c][c2] = sum_d W_o[c][h*64+d] * W_v[h*64+d][c2]
// ---------------------------------------------------------------------------
__global__ __launch_bounds__(448) void setup_kernel(
    const float* __restrict__ Wq, const float* __restrict__ Wk,
    const float* __restrict__ Wv, const float* __restrict__ Wo,
    float* __restrict__ AM) {
  const int e = threadIdx.x;
  if (e >= 392) return;
  const int which = e / 196;
  const int r = e % 196;
  const int h = r / 49;
  const int rr = r % 49;
  const int c = rr / 7;
  const int c2 = rr % 7;
  float s = 0.0f;
  if (which == 0) {
    for (int d = 0; d < 64; ++d)
      s = fmaf(Wq[(h * 64 + d) * 7 + c], Wk[(h * 64 + d) * 7 + c2], s);
  } else {
    for (int d = 0; d < 64; ++d)
      s = fmaf(Wo[c * 256 + h * 64 + d], Wv[(h * 64 + d) * 7 + c2], s);
  }
  AM[e] = s;
}

// ---------------------------------------------------------------------------
// Fused kernel R7: 1024 threads (16 waves), 32 frames/block, 2 frames/wave.
//  - Wfc staged ONCE per block into LDS (56 KB): inner loop has only 2 lf
//    VMEM loads (prefetched) + 7 ds_read_b128 -> vmcnt queue = lf only.
//  - lean VGPR (acc 14 + cur/nxt 16) -> 16 waves/block, 2 blocks/CU
//    (LDS 63.5 KB x2 = 127 KB < 160 KB) = 32 waves/CU of concurrency.
//  - phase 2: collapsed 7x7 attention + LN + FFN (proven), AM from global.
// ---------------------------------------------------------------------------
__global__ __launch_bounds__(NTHR) void fused_kernel(
    const float* __restrict__ lf,    // (T, 2048)
    const float* __restrict__ Wfc,   // (7, 2048)
    const float* __restrict__ x,     // (7, T)
    const float* __restrict__ AM,    // 392
    const float* __restrict__ W1,    // (64, 7)
    const float* __restrict__ W2,    // (7, 64)
    const float* __restrict__ ln1g, const float* __restrict__ ln1b,
    const float* __restrict__ ln2g, const float* __restrict__ ln2b,
    float* __restrict__ out) {       // (T, 7)
  __shared__ float wfc_s[7 * FDIM];            // 57344 B
  __shared__ float ft[(FPB + LQ - 1) * 7];     // 61 x 7 = 1708 B
  __shared__ float feas_s[FPB][7];             // 896 B
  __shared__ float hpart[FPB][4][7];           // 3584 B

  const int tid = threadIdx.x;
  const int lane = tid & 63;
  const int wave = tid >> 6;
  const int t0 = blockIdx.x * FPB;

  // ---- stage Wfc (float4, coalesced: 14 float4/thread), ft window ----
  {
    const float4* wsrc = (const float4*)Wfc;
    float4* wdst = (float4*)wfc_s;
    for (int i = tid; i < 7 * (FDIM / 4); i += NTHR) wdst[i] = wsrc[i];
  }
  for (int i = tid; i < (FPB + LQ - 1) * 7; i += NTHR) {
    const int row = i / 7, c = i % 7;
    const int s = t0 - (LQ - 1) + row;
    ft[i] = (s >= 0) ? x[c * T_FRAMES + s] : 0.0f;
  }
  __syncthreads();   // wfc_s ready

  // ---- phase 1: feas, 2 frames/wave, prefetched chunk loop ----
  const int tf = t0 + wave * FPW;
  const float* lfp0 = lf + (size_t)tf * FDIM;
  const float* lfp1 = lfp0 + FDIM;
  const int fl = lane * 4;

  float acc0[7], acc1[7];
#pragma unroll
  for (int c = 0; c < 7; ++c) { acc0[c] = 0.0f; acc1[c] = 0.0f; }

  float4 c0 = *(const float4*)(lfp0 + fl);
  float4 c1 = *(const float4*)(lfp1 + fl);
#pragma unroll
  for (int chunk = 0; chunk < 8; ++chunk) {
    float4 n0, n1;
    if (chunk < 7) {
      const int fn = (chunk + 1) * 256 + fl;
      n0 = *(const float4*)(lfp0 + fn);
      n1 = *(const float4*)(lfp1 + fn);
    }
    const int f = chunk * 256 + fl;
#pragma unroll
    for (int c = 0; c < 7; ++c) {
      const float4 w = *(const float4*)(&wfc_s[c * FDIM + f]);
      acc0[c] = fmaf(c0.x, w.x, fmaf(c0.y, w.y, fmaf(c0.z, w.z, fmaf(c0.w, w.w, acc0[c]))));
      acc1[c] = fmaf(c1.x, w.x, fmaf(c1.y, w.y, fmaf(c1.z, w.z, fmaf(c1.w, w.w, acc1[c]))));
    }
    if (chunk < 7) { c0 = n0; c1 = n1; }
  }

#pragma unroll
  for (int c = 0; c < 7; ++c) {
    float v0 = acc0[c], v1 = acc1[c];
    for (int off = 32; off > 0; off >>= 1) {
      v0 += __shfl_down(v0, off, 64);
      v1 += __shfl_down(v1, off, 64);
    }
    if (lane == 0) {
      feas_s[wave * FPW + 0][c] = tanhf(v0);
      feas_s[wave * FPW + 1][c] = tanhf(v1);
    }
  }
  __syncthreads();

  // ---- phase 2a: (frame, head) lanes; AM straight from global (L2) ----
  if (tid < FPB * 4) {
    const int f = tid >> 2;   // local frame 0..31
    const int h = tid & 3;    // head
    float fe[7];
#pragma unroll
    for (int c = 0; c < 7; ++c) fe[c] = feas_s[f][c];

    const float* Ah = AM + h * 49;
    const float* Mh = AM + 196 + h * 49;
    float qk[7];
#pragma unroll
    for (int c2 = 0; c2 < 7; ++c2) {
      float s = 0.0f;
#pragma unroll
      for (int c = 0; c < 7; ++c) s = fmaf(fe[c], Ah[c * 7 + c2], s);
      qk[c2] = s * 0.125f;
    }
    const float* frow = &ft[f * 7];
    float sc[LQ];
    float m = -1e30f;
#pragma unroll
    for (int j = 0; j < LQ; ++j) {
      const float* r = frow + j * 7;
      float s = 0.0f;
#pragma unroll
      for (int c2 = 0; c2 < 7; ++c2) s = fmaf(qk[c2], r[c2], s);
      sc[j] = s;
      m = fmaxf(m, s);
    }
    float sum = 0.0f;
    float wsum[7] = {0, 0, 0, 0, 0, 0, 0};
#pragma unroll
    for (int j = 0; j < LQ; ++j) {
      const float p = __expf(sc[j] - m);
      sum += p;
      const float* r = frow + j * 7;
#pragma unroll
      for (int c2 = 0; c2 < 7; ++c2) wsum[c2] = fmaf(p, r[c2], wsum[c2]);
    }
    const float inv = 1.0f / sum;
#pragma unroll
    for (int c = 0; c < 7; ++c) {
      float s = 0.0f;
#pragma unroll
      for (int c2 = 0; c2 < 7; ++c2) s = fmaf(Mh[c * 7 + c2], wsum[c2], s);
      hpart[f][h][c] = s * inv;
    }
  }
  __syncthreads();

  // ---- phase 2b: per-frame epilogue ----
  if (tid < FPB) {
    const int f = tid;
    float v[7];
#pragma unroll
    for (int c = 0; c < 7; ++c)
      v[c] = feas_s[f][c] + hpart[f][0][c] + hpart[f][1][c] + hpart[f][2][c] + hpart[f][3][c];

    float mu = 0.0f;
#pragma unroll
    for (int c = 0; c < 7; ++c) mu += v[c];
    mu *= (1.0f / 7.0f);
    float var = 0.0f;
#pragma unroll
    for (int c = 0; c < 7; ++c) { const float d = v[c] - mu; var = fmaf(d, d, var); }
    var *= (1.0f / 7.0f);
    float rs = rsqrtf(var + 1e-5f);
    float o1[7];
#pragma unroll
    for (int c = 0; c < 7; ++c) o1[c] = (v[c] - mu) * rs * ln1g[c] + ln1b[c];

    float ff[7] = {0, 0, 0, 0, 0, 0, 0};
    for (int k = 0; k < 64; ++k) {
      float hk = 0.0f;
#pragma unroll
      for (int c = 0; c < 7; ++c) hk = fmaf(W1[k * 7 + c], o1[c], hk);
      hk = fmaxf(hk, 0.0f);
#pragma unroll
      for (int c = 0; c < 7; ++c) ff[c] = fmaf(W2[c * 64 + k], hk, ff[c]);
    }

#pragma unroll
    for (int c = 0; c < 7; ++c) v[c] = ff[c] + o1[c];
    mu = 0.0f;
#pragma unroll
    for (int c = 0; c < 7; ++c) mu += v[c];
    mu *= (1.0f / 7.0f);
    var = 0.0f;
#pragma unroll
    for (int c = 0; c < 7; ++c) { const float d = v[c] - mu; var = fmaf(d, d, var); }
    var *= (1.0f / 7.0f);
    rs = rsqrtf(var + 1e-5f);
    const int t = t0 + f;
#pragma unroll
    for (int c = 0; c < 7; ++c)
      out[(size_t)t * 7 + c] = (v[c] - mu) * rs * ln2g[c] + ln2b[c];
  }
}

// ---------------------------------------------------------------------------
extern "C" void kernel_launch(void* const* d_in, const int* in_sizes, int n_in,
                              void* d_out, int out_size, void* d_ws, size_t ws_size,
                              hipStream_t stream) {
  const float* x    = (const float*)d_in[0];   // (1, 7, T)
  const float* lf   = (const float*)d_in[1];   // (1, T, 2048)
  const float* Wfc  = (const float*)d_in[2];   // (7, 2048)
  const float* Wq   = (const float*)d_in[3];   // (256, 7)
  const float* Wk   = (const float*)d_in[4];   // (256, 7)
  const float* Wv   = (const float*)d_in[5];   // (256, 7)
  const float* Wo   = (const float*)d_in[6];   // (7, 256)
  const float* ln1g = (const float*)d_in[7];
  const float* ln1b = (const float*)d_in[8];
  const float* W1   = (const float*)d_in[9];   // (64, 7)
  const float* W2   = (const float*)d_in[10];  // (7, 64)
  const float* ln2g = (const float*)d_in[11];
  const float* ln2b = (const float*)d_in[12];
  float* out = (float*)d_out;

  float* AM = (float*)d_ws;   // 392 floats

  setup_kernel<<<1, 448, 0, stream>>>(Wq, Wk, Wv, Wo, AM);
  fused_kernel<<<T_FRAMES / FPB, NTHR, 0, stream>>>(
      lf, Wfc, x, AM, W1, W2, ln1g, ln1b, ln2g, ln2b, out);
}

// Round 8
// 289.091 us; speedup vs baseline: 1.3759x; 1.3759x over previous
//
#include <hip/hip_runtime.h>
#include <math.h>

#define T_FRAMES 16384
#define FDIM 2048
#define LQ 30
#define FPB 16    // frames per block
#define NTHR 512  // 8 waves
#define FPW 2     // frames per wave

// ---------------------------------------------------------------------------
// Kernel 0: precompute per-head 7x7 bilinear forms (proven R1/R3/R5/R7)
// ---------------------------------------------------------------------------
__global__ __launch_bounds__(448) void setup_kernel(
    const float* __restrict__ Wq, const float* __restrict__ Wk,
    const float* __restrict__ Wv, const float* __restrict__ Wo,
    float* __restrict__ AM) {
  const int e = threadIdx.x;
  if (e >= 392) return;
  const int which = e / 196;
  const int r = e % 196;
  const int h = r / 49;
  const int rr = r % 49;
  const int c = rr / 7;
  const int c2 = rr % 7;
  float s = 0.0f;
  if (which == 0) {
    for (int d = 0; d < 64; ++d)
      s = fmaf(Wq[(h * 64 + d) * 7 + c], Wk[(h * 64 + d) * 7 + c2], s);
  } else {
    for (int d = 0; d < 64; ++d)
      s = fmaf(Wo[c * 256 + h * 64 + d], Wv[(h * 64 + d) * 7 + c2], s);
  }
  AM[e] = s;
}

// ---------------------------------------------------------------------------
// Fused kernel R8: 512 threads (8 waves), 16 frames/block, 2 frames/wave.
//  - Wfc in LDS (56 KB); LDS total ~61 KB -> 2 blocks/CU = 16 waves/CU.
//  - lean regs (acc 14 + cur/nxt 16): no spill (R7's 1024-thr cap spilled:
//    VGPR=64, WRITE_SIZE 337 MB). No forced min-occupancy (R4 lesson).
//  - inner loop vmcnt queue holds only prefetched lf loads.
// ---------------------------------------------------------------------------
__global__ __launch_bounds__(NTHR) void fused_kernel(
    const float* __restrict__ lf,    // (T, 2048)
    const float* __restrict__ Wfc,   // (7, 2048)
    const float* __restrict__ x,     // (7, T)
    const float* __restrict__ AM,    // 392
    const float* __restrict__ W1,    // (64, 7)
    const float* __restrict__ W2,    // (7, 64)
    const float* __restrict__ ln1g, const float* __restrict__ ln1b,
    const float* __restrict__ ln2g, const float* __restrict__ ln2b,
    float* __restrict__ out) {       // (T, 7)
  __shared__ float wfc_s[7 * FDIM];            // 57344 B
  __shared__ float ft[(FPB + LQ - 1) * 7];     // 45 x 7 = 1260 B
  __shared__ float feas_s[FPB][7];             // 448 B
  __shared__ float hpart[FPB][4][7];           // 1792 B

  const int tid = threadIdx.x;
  const int lane = tid & 63;
  const int wave = tid >> 6;
  const int t0 = blockIdx.x * FPB;

  // ---- stage Wfc (float4 coalesced, 7 per thread), ft window ----
  {
    const float4* wsrc = (const float4*)Wfc;
    float4* wdst = (float4*)wfc_s;
    for (int i = tid; i < 7 * (FDIM / 4); i += NTHR) wdst[i] = wsrc[i];
  }
  for (int i = tid; i < (FPB + LQ - 1) * 7; i += NTHR) {
    const int row = i / 7, c = i % 7;
    const int s = t0 - (LQ - 1) + row;
    ft[i] = (s >= 0) ? x[c * T_FRAMES + s] : 0.0f;
  }
  __syncthreads();   // wfc_s ready

  // ---- phase 1: feas, 2 frames/wave, prefetched chunk loop ----
  const int tf = t0 + wave * FPW;
  const float* lfp0 = lf + (size_t)tf * FDIM;
  const float* lfp1 = lfp0 + FDIM;
  const int fl = lane * 4;

  float acc0[7], acc1[7];
#pragma unroll
  for (int c = 0; c < 7; ++c) { acc0[c] = 0.0f; acc1[c] = 0.0f; }

  float4 c0 = *(const float4*)(lfp0 + fl);
  float4 c1 = *(const float4*)(lfp1 + fl);
#pragma unroll
  for (int chunk = 0; chunk < 8; ++chunk) {
    float4 n0, n1;
    if (chunk < 7) {
      const int fn = (chunk + 1) * 256 + fl;
      n0 = *(const float4*)(lfp0 + fn);
      n1 = *(const float4*)(lfp1 + fn);
    }
    const int f = chunk * 256 + fl;
#pragma unroll
    for (int c = 0; c < 7; ++c) {
      const float4 w = *(const float4*)(&wfc_s[c * FDIM + f]);
      acc0[c] = fmaf(c0.x, w.x, fmaf(c0.y, w.y, fmaf(c0.z, w.z, fmaf(c0.w, w.w, acc0[c]))));
      acc1[c] = fmaf(c1.x, w.x, fmaf(c1.y, w.y, fmaf(c1.z, w.z, fmaf(c1.w, w.w, acc1[c]))));
    }
    if (chunk < 7) { c0 = n0; c1 = n1; }
  }

#pragma unroll
  for (int c = 0; c < 7; ++c) {
    float v0 = acc0[c], v1 = acc1[c];
    for (int off = 32; off > 0; off >>= 1) {
      v0 += __shfl_down(v0, off, 64);
      v1 += __shfl_down(v1, off, 64);
    }
    if (lane == 0) {
      feas_s[wave * FPW + 0][c] = tanhf(v0);
      feas_s[wave * FPW + 1][c] = tanhf(v1);
    }
  }
  __syncthreads();

  // ---- phase 2a: (frame, head) lanes; AM from global (L2-broadcast) ----
  if (tid < FPB * 4) {
    const int f = tid >> 2;   // local frame 0..15
    const int h = tid & 3;    // head
    float fe[7];
#pragma unroll
    for (int c = 0; c < 7; ++c) fe[c] = feas_s[f][c];

    const float* Ah = AM + h * 49;
    const float* Mh = AM + 196 + h * 49;
    float qk[7];
#pragma unroll
    for (int c2 = 0; c2 < 7; ++c2) {
      float s = 0.0f;
#pragma unroll
      for (int c = 0; c < 7; ++c) s = fmaf(fe[c], Ah[c * 7 + c2], s);
      qk[c2] = s * 0.125f;
    }
    const float* frow = &ft[f * 7];
    float sc[LQ];
    float m = -1e30f;
#pragma unroll
    for (int j = 0; j < LQ; ++j) {
      const float* r = frow + j * 7;
      float s = 0.0f;
#pragma unroll
      for (int c2 = 0; c2 < 7; ++c2) s = fmaf(qk[c2], r[c2], s);
      sc[j] = s;
      m = fmaxf(m, s);
    }
    float sum = 0.0f;
    float wsum[7] = {0, 0, 0, 0, 0, 0, 0};
#pragma unroll
    for (int j = 0; j < LQ; ++j) {
      const float p = __expf(sc[j] - m);
      sum += p;
      const float* r = frow + j * 7;
#pragma unroll
      for (int c2 = 0; c2 < 7; ++c2) wsum[c2] = fmaf(p, r[c2], wsum[c2]);
    }
    const float inv = 1.0f / sum;
#pragma unroll
    for (int c = 0; c < 7; ++c) {
      float s = 0.0f;
#pragma unroll
      for (int c2 = 0; c2 < 7; ++c2) s = fmaf(Mh[c * 7 + c2], wsum[c2], s);
      hpart[f][h][c] = s * inv;
    }
  }
  __syncthreads();

  // ---- phase 2b: per-frame epilogue ----
  if (tid < FPB) {
    const int f = tid;
    float v[7];
#pragma unroll
    for (int c = 0; c < 7; ++c)
      v[c] = feas_s[f][c] + hpart[f][0][c] + hpart[f][1][c] + hpart[f][2][c] + hpart[f][3][c];

    float mu = 0.0f;
#pragma unroll
    for (int c = 0; c < 7; ++c) mu += v[c];
    mu *= (1.0f / 7.0f);
    float var = 0.0f;
#pragma unroll
    for (int c = 0; c < 7; ++c) { const float d = v[c] - mu; var = fmaf(d, d, var); }
    var *= (1.0f / 7.0f);
    float rs = rsqrtf(var + 1e-5f);
    float o1[7];
#pragma unroll
    for (int c = 0; c < 7; ++c) o1[c] = (v[c] - mu) * rs * ln1g[c] + ln1b[c];

    float ff[7] = {0, 0, 0, 0, 0, 0, 0};
    for (int k = 0; k < 64; ++k) {
      float hk = 0.0f;
#pragma unroll
      for (int c = 0; c < 7; ++c) hk = fmaf(W1[k * 7 + c], o1[c], hk);
      hk = fmaxf(hk, 0.0f);
#pragma unroll
      for (int c = 0; c < 7; ++c) ff[c] = fmaf(W2[c * 64 + k], hk, ff[c]);
    }

#pragma unroll
    for (int c = 0; c < 7; ++c) v[c] = ff[c] + o1[c];
    mu = 0.0f;
#pragma unroll
    for (int c = 0; c < 7; ++c) mu += v[c];
    mu *= (1.0f / 7.0f);
    var = 0.0f;
#pragma unroll
    for (int c = 0; c < 7; ++c) { const float d = v[c] - mu; var = fmaf(d, d, var); }
    var *= (1.0f / 7.0f);
    rs = rsqrtf(var + 1e-5f);
    const int t = t0 + f;
#pragma unroll
    for (int c = 0; c < 7; ++c)
      out[(size_t)t * 7 + c] = (v[c] - mu) * rs * ln2g[c] + ln2b[c];
  }
}

// ---------------------------------------------------------------------------
extern "C" void kernel_launch(void* const* d_in, const int* in_sizes, int n_in,
                              void* d_out, int out_size, void* d_ws, size_t ws_size,
                              hipStream_t stream) {
  const float* x    = (const float*)d_in[0];   // (1, 7, T)
  const float* lf   = (const float*)d_in[1];   // (1, T, 2048)
  const float* Wfc  = (const float*)d_in[2];   // (7, 2048)
  const float* Wq   = (const float*)d_in[3];   // (256, 7)
  const float* Wk   = (const float*)d_in[4];   // (256, 7)
  const float* Wv   = (const float*)d_in[5];   // (256, 7)
  const float* Wo   = (const float*)d_in[6];   // (7, 256)
  const float* ln1g = (const float*)d_in[7];
  const float* ln1b = (const float*)d_in[8];
  const float* W1   = (const float*)d_in[9];   // (64, 7)
  const float* W2   = (const float*)d_in[10];  // (7, 64)
  const float* ln2g = (const float*)d_in[11];
  const float* ln2b = (const float*)d_in[12];
  float* out = (float*)d_out;

  float* AM = (float*)d_ws;   // 392 floats

  setup_kernel<<<1, 448, 0, stream>>>(Wq, Wk, Wv, Wo, AM);
  fused_kernel<<<T_FRAMES / FPB, NTHR, 0, stream>>>(
      lf, Wfc, x, AM, W1, W2, ln1g, ln1b, ln2g, ln2b, out);
}